// Round 8
// baseline (127.043 us; speedup 1.0000x reference)
//
#include <hip/hip_runtime.h>

// ---------- helpers ----------
__device__ __forceinline__ unsigned short f2b(float f) {
    unsigned int u = __builtin_bit_cast(unsigned int, f);
    u += 0x7fffu + ((u >> 16) & 1u);   // round-to-nearest-even
    return (unsigned short)(u >> 16);
}
__device__ __forceinline__ float fastrcp(float x) {
    return __builtin_amdgcn_rcpf(x);   // ~1e-7 rel err, invisible under bf16
}
// packed f32x2 -> bf16x2 (RTNE, same rounding as f2b), 1 instruction
__device__ __forceinline__ unsigned int cvt_pk_bf16(float lo, float hi) {
    unsigned int r;
    asm("v_cvt_pk_bf16_f32 %0, %1, %2" : "=v"(r) : "v"(lo), "v"(hi));
    return r;
}
// DPP wave64 sum: after chain, lane 63 holds the full sum; broadcast via readlane.
template<int CTRL>
__device__ __forceinline__ float dpp_add(float x) {
    int s = __builtin_amdgcn_update_dpp(0, __builtin_bit_cast(int, x), CTRL, 0xf, 0xf, true);
    return x + __builtin_bit_cast(float, s);
}
__device__ __forceinline__ float wave_sum_bcast(float x) {
    x = dpp_add<0x111>(x);   // row_shr:1
    x = dpp_add<0x112>(x);   // row_shr:2
    x = dpp_add<0x114>(x);   // row_shr:4
    x = dpp_add<0x118>(x);   // row_shr:8  -> lane 15/31/47/63 = row sums
    x = dpp_add<0x142>(x);   // row_bcast:15
    x = dpp_add<0x143>(x);   // row_bcast:31 -> lane 63 = total
    return __builtin_bit_cast(float,
        __builtin_amdgcn_readlane(__builtin_bit_cast(int, x), 63));
}

typedef short bf16x8_t __attribute__((ext_vector_type(8)));
typedef float f32x4_t  __attribute__((ext_vector_type(4)));

#define LDS_PTR(p) ((__attribute__((address_space(3))) void*)(p))
#define GLB_PTR(p) ((const __attribute__((address_space(1))) void*)(p))

// Problem dims
#define NB   16384   // batch
#define AD   1024    // A dim
#define YD   128     // output dim

// =====================================================================
// Kernel 1: Vt in FRAGMENT-MAJOR layout (unchanged — validated).
//   Logical B row n (0..255), col a (0..1023): val = Kp[a][n>>7]*U[2a+(n>>7)][n&127]
//   Physical: T=n>>4, rr=n&15, CQ=a>>3, e=a&7
//             Vtf[T*16384 + CQ*128 + rr*8 + e]
// =====================================================================
__global__ __launch_bounds__(256) void vt_kernel(
    const float* __restrict__ Kq,   // [1024][2] f32
    const float* __restrict__ U,    // [2048][128] f32
    unsigned short* __restrict__ Vtf) // [16][128][16][8] bf16
{
    int o  = blockIdx.x * 256 + threadIdx.x;
    int T  = o >> 14;
    int CQ = (o >> 7) & 127;
    int rr = (o >> 3) & 15;
    int e  = o & 7;
    int n  = T * 16 + rr;
    int a  = CQ * 8 + e;
    int j  = n >> 7;
    int y  = n & 127;
    float k  = Kq[2 * a + j];
    float uv = U[(size_t)(2 * a + j) * YD + y];
    Vtf[o] = f2b(k * k * uv);
}

// =====================================================================
// Kernel 2: row solve -> GLOBAL af in fragment-swizzled IMAGE layout
// (unchanged — validated in round 7).
// image i covers rows i*32..i*32+31; row mm=R&31, chunk C=a>>3 at
//   elem offset  i*32768 + mm*1024 + (C>>3)*64 + ((C&7)^(R&7))*8 + (a&7)
// 1024 blocks x 512 threads (8 waves, 2 rows/wave) = 8 waves/SIMD.
// NO LDS, NO barriers: pure streaming + VALU, max TLP.
// =====================================================================
__global__ __launch_bounds__(512, 4) void row_kernel(
    const float* __restrict__ AT,            // [16384][1024] f32
    const float* __restrict__ Kq,            // [1024][2] f32
    const float* __restrict__ BTv,           // [2] f32
    unsigned short* __restrict__ afb,        // [512 images][32768] bf16
    float* __restrict__ bff)                 // [16384][2] f32
{
    const int t    = threadIdx.x;
    const int lane = t & 63;
    const int w    = t >> 6;                  // wave id 0..7
    const int R0   = blockIdx.x * 16 + w * 2; // wave owns rows R0, R0+1

    // lane owns columns a = c*256 + lane*4 + e, c=0..3, e=0..3
    float kp0[16], kp1[16];
#pragma unroll
    for (int c = 0; c < 4; ++c) {
        int base = c * 256 + lane * 4;
        float4 k0v = *(const float4*)(Kq + 2 * base);
        float4 k1v = *(const float4*)(Kq + 2 * base + 4);
        kp0[c * 4 + 0] = k0v.x * k0v.x; kp1[c * 4 + 0] = k0v.y * k0v.y;
        kp0[c * 4 + 1] = k0v.z * k0v.z; kp1[c * 4 + 1] = k0v.w * k0v.w;
        kp0[c * 4 + 2] = k1v.x * k1v.x; kp1[c * 4 + 2] = k1v.y * k1v.y;
        kp0[c * 4 + 3] = k1v.z * k1v.z; kp1[c * 4 + 3] = k1v.w * k1v.w;
    }
    const float bt0 = BTv[0], bt1 = BTv[1];

    const float* atb = AT + (size_t)R0 * AD;

    float ta[2][16];   // both rows loaded upfront (8 independent dwordx4)
#pragma unroll
    for (int r = 0; r < 2; ++r) {
#pragma unroll
        for (int c = 0; c < 4; ++c) {
            float4 av = *(const float4*)(atb + (size_t)r * AD + c * 256 + lane * 4);
            ta[r][c * 4 + 0] = av.x; ta[r][c * 4 + 1] = av.y;
            ta[r][c * 4 + 2] = av.z; ta[r][c * 4 + 3] = av.w;
        }
    }

#pragma unroll
    for (int r = 0; r < 2; ++r) {
        // moments: 0:M0 1:M1 2:M00 3:M01 4:M11 5:M000 6:M001 7:M011 8:M111
        float M[9];
#pragma unroll
        for (int i2 = 0; i2 < 9; ++i2) M[i2] = 0.f;
#pragma unroll
        for (int e = 0; e < 16; ++e) {
            float tv = ta[r][e], p = kp0[e], q2 = kp1[e];
            float u0 = tv * p, u1 = tv * q2;
            M[0] += u0; M[1] += u1;
            float u00 = u0 * p, u01 = u0 * q2, u11 = u1 * q2;
            M[2] += u00; M[3] += u01; M[4] += u11;
            M[5] += u00 * p; M[6] += u00 * q2; M[7] += u01 * q2; M[8] += u11 * q2;
        }
        // DPP reduce (no DS ops), result uniform via readlane
#pragma unroll
        for (int i2 = 0; i2 < 9; ++i2) M[i2] = wave_sum_bcast(M[i2]);

        float bf0 = 0.f, bf1 = 0.f;
#pragma unroll
        for (int it = 0; it < 8; ++it) {
            float q00 = bf0 * bf0, q01 = bf0 * bf1, q11 = bf1 * bf1;
            float s0 = M[0] - (bf0 * M[2] + bf1 * M[3]) + (q00 * M[5] + 2.f * q01 * M[6] + q11 * M[7]);
            float s1 = M[1] - (bf0 * M[3] + bf1 * M[4]) + (q00 * M[6] + 2.f * q01 * M[7] + q11 * M[8]);
            bf0 = bt0 * fastrcp(1.f + s0);
            bf1 = bt1 * fastrcp(1.f + s1);
        }
        const int R = R0 + r;
        if (lane == 0) { bff[(size_t)R * 2] = bf0; bff[(size_t)R * 2 + 1] = bf1; }

        // af -> bf16 (cvt_pk, RTNE) -> swizzled global image (validated)
        unsigned short* base = afb + (size_t)(R >> 5) * 32768 + (size_t)(R & 31) * 1024;
        const int s7 = R & 7;
#pragma unroll
        for (int c = 0; c < 4; ++c) {
            float v[4];
#pragma unroll
            for (int e = 0; e < 4; ++e) {
                int idx = c * 4 + e;
                v[e] = ta[r][idx] * fastrcp(1.f + bf0 * kp0[idx] + bf1 * kp1[idx]);
            }
            uint2 pk;
            pk.x = cvt_pk_bf16(v[0], v[1]);
            pk.y = cvt_pk_bf16(v[2], v[3]);
            int cg = c * 4 + (lane >> 4);
            int cl = (lane >> 1) & 7;
            int off = (cg * 8 + (cl ^ s7)) * 8 + (lane & 1) * 4;
            *(uint2*)(base + off) = pk;
        }
    }
}

// =====================================================================
// Kernel 3: GEMM + combine, BM=64. 256 blocks (1/CU), 512 threads.
// Stages TWO consecutive 64KB af images (contiguous 128 KB, linear copy)
// into a 128 KB LDS tile, split into two K-halves:
//   stage(h0); bar; [issue stage(h1); compute K<512]; bar; compute K>=512
// so half the A-stage latency hides under half-0 MFMA.
// Wave (h,q) = (w>>2, w&3): h picks image/row-half (rows h*32..h*32+31 —
// each wave reads ONLY its own image), q picks n-tiles {q,q+4,q+8,q+12}.
// B L2 traffic = 256 blocks x 512 KB = 128 MB (4x less than round 7),
// and the two h-waves with equal q share B fragments via L1.
// fa read formula identical to validated round 7 (swizzle key r&7==rr&7
// for all row groups since offsets are multiples of 16).
// =====================================================================
__global__ __launch_bounds__(512, 2) void gemm_kernel(
    const unsigned short* __restrict__ afb,  // [512 images][32768] bf16
    const unsigned short* __restrict__ Vtf,  // fragment-major bf16
    const float* __restrict__ bff,           // [16384][2] f32
    const float* __restrict__ bias,          // [128] f32
    float* __restrict__ out)                 // [16384][128] f32
{
    __shared__ __align__(16) unsigned short lA[64 * 1024];   // 128 KB

    const int t    = threadIdx.x;
    const int lane = t & 63;
    const int w    = t >> 6;        // wave id 0..7
    const int mtile = blockIdx.x;   // 0..255

    const unsigned short* img = afb + (size_t)mtile * 65536;  // 2 images, contiguous

    // stage K-half hh: per row (64 rows), 512 elems (1 KB) at row*1024 + hh*512.
    // 4096 16B slots per half, 8 per thread; linear src == dst offsets.
    auto stage = [&](int hh) {
#pragma unroll
        for (int i = 0; i < 8; ++i) {
            int s = i * 512 + t;                       // 0..4095
            int off = (s >> 6) * 1024 + hh * 512 + (s & 63) * 8;
            __builtin_amdgcn_global_load_lds(GLB_PTR(img + off), LDS_PTR(&lA[off]), 16, 0, 0);
        }
    };

    const int rr = lane & 15;      // row/col within 16-tile
    const int hb = lane >> 4;      // quarter-wave
    const int rx = rr & 7;         // A-swizzle key
    const int q  = w & 3;          // n-quad: tiles {q, q+4, q+8, q+12}
    const int h  = w >> 2;         // row-half: rows h*32 .. h*32+31 (image h)

    const unsigned short* pB = Vtf + (size_t)q * 16384 + hb * 128 + rr * 8;

    stage(0);

    f32x4_t acc[2][4];
#pragma unroll
    for (int i = 0; i < 2; ++i)
#pragma unroll
        for (int j = 0; j < 4; ++j) acc[i][j] = (f32x4_t){0.f, 0.f, 0.f, 0.f};

    bf16x8_t fbA[4], fbB[4];

    auto loadB = [&](bf16x8_t* fb, int k0, int kk) {
        int ke = k0 * 16 + kk * 512;              // uniform elem offset
        fb[0] = *(const bf16x8_t*)(pB + ke);            // tile q
        fb[1] = *(const bf16x8_t*)(pB + ke + 65536);    // tile q+4
        fb[2] = *(const bf16x8_t*)(pB + ke + 131072);   // tile q+8
        fb[3] = *(const bf16x8_t*)(pB + ke + 196608);   // tile q+12
    };
    auto compute = [&](const bf16x8_t* fb, int k0, int kk) {
        const int cq = kk * 4 + hb;
        bf16x8_t fa[2];
#pragma unroll
        for (int i = 0; i < 2; ++i) {
            int r = h * 32 + i * 16 + rr;
            fa[i] = *(const bf16x8_t*)(&lA[((r * 128) + (k0 >> 6) * 8 + (cq ^ rx)) * 8]);
        }
#pragma unroll
        for (int i = 0; i < 2; ++i)
#pragma unroll
            for (int j = 0; j < 4; ++j)
                acc[i][j] = __builtin_amdgcn_mfma_f32_16x16x32_bf16(fa[i], fb[j], acc[i][j], 0, 0, 0);
    };

    loadB(fbA, 0, 0);
    loadB(fbB, 0, 1);
    __syncthreads();   // drains vmcnt(0): half 0 of lA ready
    stage(1);          // issue half-1 stage; drains at next barrier

#pragma unroll 1
    for (int k0 = 0; k0 < 512; k0 += 64) {
        __builtin_amdgcn_s_setprio(1);
        compute(fbA, k0, 0);
        __builtin_amdgcn_s_setprio(0);
        loadB(fbA, k0 + 64, 0);
        __builtin_amdgcn_s_setprio(1);
        compute(fbB, k0, 1);
        __builtin_amdgcn_s_setprio(0);
        loadB(fbB, k0 + 64, 1);
    }
    __syncthreads();   // drains vmcnt(0): half 1 of lA ready
#pragma unroll 1
    for (int k0 = 512; k0 < AD; k0 += 64) {
        __builtin_amdgcn_s_setprio(1);
        compute(fbA, k0, 0);
        __builtin_amdgcn_s_setprio(0);
        if (k0 + 64 < AD) loadB(fbA, k0 + 64, 0);
        __builtin_amdgcn_s_setprio(1);
        compute(fbB, k0, 1);
        __builtin_amdgcn_s_setprio(0);
        if (k0 + 64 < AD) loadB(fbB, k0 + 64, 1);
    }

    // epilogue: C/D layout col = lane&15 (n), row = (lane>>4)*4 + reg (m).
    // pairs: (acc[i][0], acc[i][2]) at y=q*16+rr; (acc[i][1], acc[i][3]) at y+64... 
    // tile q+4 is y=q*16+64; its +128 partner is tile q+12.
#pragma unroll
    for (int i = 0; i < 2; ++i) {
        int mbase = mtile * 64 + h * 32 + i * 16 + hb * 4;
        float2 bfv[4];
#pragma unroll
        for (int r = 0; r < 4; ++r)
            bfv[r] = *(const float2*)(bff + (size_t)(mbase + r) * 2);
#pragma unroll
        for (int jj = 0; jj < 2; ++jj) {
            int y = q * 16 + jj * 64 + rr;          // jj=0: tile q; jj=1: tile q+4
            float bv = bias[y];
#pragma unroll
            for (int r = 0; r < 4; ++r) {
                float val = bfv[r].x * acc[i][jj][r] + bfv[r].y * acc[i][jj + 2][r] + bv;
                out[(size_t)(mbase + r) * YD + y] = val;
            }
        }
    }
}

// =====================================================================
extern "C" void kernel_launch(void* const* d_in, const int* in_sizes, int n_in,
                              void* d_out, int out_size, void* d_ws, size_t ws_size,
                              hipStream_t stream) {
    const float* AT  = (const float*)d_in[0];  // [16384][1024] f32
    const float* Kq  = (const float*)d_in[1];  // [1024][2] f32
    const float* BTv = (const float*)d_in[2];  // [2] f32
    const float* U   = (const float*)d_in[3];  // [2048][128] f32
    const float* bia = (const float*)d_in[4];  // [128] f32
    float* out = (float*)d_out;

    char* ws = (char*)d_ws;
    unsigned short* Vtf = (unsigned short*)ws;                    // 512 KB
    unsigned short* afb = (unsigned short*)(ws + 524288);         // 32 MB
    float*          bff = (float*)(ws + 524288 + 33554432);       // 128 KB

    vt_kernel <<<dim3(1024), dim3(256), 0, stream>>>(Kq, U, Vtf);
    row_kernel <<<dim3(NB / 16), dim3(512), 0, stream>>>(AT, Kq, BTv, afb, bff);
    gemm_kernel<<<dim3(NB / 64), dim3(512), 0, stream>>>(afb, Vtf, bff, bia, out);
}

// Round 9
// 123.878 us; speedup vs baseline: 1.0255x; 1.0255x over previous
//
#include <hip/hip_runtime.h>

// ---------- helpers ----------
__device__ __forceinline__ unsigned short f2b(float f) {
    unsigned int u = __builtin_bit_cast(unsigned int, f);
    u += 0x7fffu + ((u >> 16) & 1u);   // round-to-nearest-even
    return (unsigned short)(u >> 16);
}
__device__ __forceinline__ float fastrcp(float x) {
    return __builtin_amdgcn_rcpf(x);   // ~1e-7 rel err, invisible under bf16
}
// packed f32x2 -> bf16x2 (RTNE, same rounding as f2b), 1 instruction
__device__ __forceinline__ unsigned int cvt_pk_bf16(float lo, float hi) {
    unsigned int r;
    asm("v_cvt_pk_bf16_f32 %0, %1, %2" : "=v"(r) : "v"(lo), "v"(hi));
    return r;
}
// DPP wave64 sum: after chain, lane 63 holds the full sum; broadcast via readlane.
template<int CTRL>
__device__ __forceinline__ float dpp_add(float x) {
    int s = __builtin_amdgcn_update_dpp(0, __builtin_bit_cast(int, x), CTRL, 0xf, 0xf, true);
    return x + __builtin_bit_cast(float, s);
}
__device__ __forceinline__ float wave_sum_bcast(float x) {
    x = dpp_add<0x111>(x);   // row_shr:1
    x = dpp_add<0x112>(x);   // row_shr:2
    x = dpp_add<0x114>(x);   // row_shr:4
    x = dpp_add<0x118>(x);   // row_shr:8  -> lane 15/31/47/63 = row sums
    x = dpp_add<0x142>(x);   // row_bcast:15
    x = dpp_add<0x143>(x);   // row_bcast:31 -> lane 63 = total
    return __builtin_bit_cast(float,
        __builtin_amdgcn_readlane(__builtin_bit_cast(int, x), 63));
}

typedef short bf16x8_t __attribute__((ext_vector_type(8)));
typedef float f32x4_t  __attribute__((ext_vector_type(4)));

#define LDS_PTR(p) ((__attribute__((address_space(3))) void*)(p))
#define GLB_PTR(p) ((const __attribute__((address_space(1))) void*)(p))

// Problem dims
#define NB   16384   // batch
#define AD   1024    // A dim
#define YD   128     // output dim

// =====================================================================
// Kernel 1 (MERGED prep): row solve -> swizzled af images + bff (R7
// validated body, unchanged), PLUS the Vt fragment-major build (R7/R8
// validated vt_kernel body) folded onto blocks 0..511 as a side-job.
// Both products are only consumed by the gemm launch -> ordering safe.
// 1024 blocks x 512 threads (8 waves, 2 rows/wave). NO LDS, NO barriers.
//
// af image layout: image i covers rows i*32..i*32+31; row mm=R&31,
//   chunk C=a>>3 at elem off i*32768 + mm*1024 + (C>>3)*64
//                            + ((C&7)^(R&7))*8 + (a&7)
// Vtf fragment-major: T=n>>4, rr=n&15, CQ=a>>3, e=a&7:
//   Vtf[T*16384 + CQ*128 + rr*8 + e] = Kp[a][n>>7] * U[2a+(n>>7)][n&127]
// =====================================================================
__global__ __launch_bounds__(512, 4) void prep_kernel(
    const float* __restrict__ AT,            // [16384][1024] f32
    const float* __restrict__ Kq,            // [1024][2] f32
    const float* __restrict__ BTv,           // [2] f32
    const float* __restrict__ U,             // [2048][128] f32
    unsigned short* __restrict__ Vtf,        // [16][128][16][8] bf16
    unsigned short* __restrict__ afb,        // [512 images][32768] bf16
    float* __restrict__ bff)                 // [16384][2] f32
{
    const int t    = threadIdx.x;
    const int lane = t & 63;
    const int w    = t >> 6;                  // wave id 0..7
    const int R0   = blockIdx.x * 16 + w * 2; // wave owns rows R0, R0+1

    // lane owns columns a = c*256 + lane*4 + e, c=0..3, e=0..3
    float kp0[16], kp1[16];
#pragma unroll
    for (int c = 0; c < 4; ++c) {
        int base = c * 256 + lane * 4;
        float4 k0v = *(const float4*)(Kq + 2 * base);
        float4 k1v = *(const float4*)(Kq + 2 * base + 4);
        kp0[c * 4 + 0] = k0v.x * k0v.x; kp1[c * 4 + 0] = k0v.y * k0v.y;
        kp0[c * 4 + 1] = k0v.z * k0v.z; kp1[c * 4 + 1] = k0v.w * k0v.w;
        kp0[c * 4 + 2] = k1v.x * k1v.x; kp1[c * 4 + 2] = k1v.y * k1v.y;
        kp0[c * 4 + 3] = k1v.z * k1v.z; kp1[c * 4 + 3] = k1v.w * k1v.w;
    }
    const float bt0 = BTv[0], bt1 = BTv[1];

    const float* atb = AT + (size_t)R0 * AD;

    float ta[2][16];   // both rows loaded upfront (8 independent dwordx4)
#pragma unroll
    for (int r = 0; r < 2; ++r) {
#pragma unroll
        for (int c = 0; c < 4; ++c) {
            float4 av = *(const float4*)(atb + (size_t)r * AD + c * 256 + lane * 4);
            ta[r][c * 4 + 0] = av.x; ta[r][c * 4 + 1] = av.y;
            ta[r][c * 4 + 2] = av.z; ta[r][c * 4 + 3] = av.w;
        }
    }

    // ---- vt side-job (blocks 0..511, 1 elem/thread; validated formula).
    // Placed after the ta loads so AT traffic is already in flight.
    if (blockIdx.x < 512) {
        int o  = blockIdx.x * 512 + t;   // 0..262143
        int T  = o >> 14;
        int CQ = (o >> 7) & 127;
        int vr = (o >> 3) & 15;
        int e  = o & 7;
        int n  = T * 16 + vr;
        int a  = CQ * 8 + e;
        int j  = n >> 7;
        int y  = n & 127;
        float k  = Kq[2 * a + j];
        float uv = U[(size_t)(2 * a + j) * YD + y];
        Vtf[o] = f2b(k * k * uv);
    }

#pragma unroll
    for (int r = 0; r < 2; ++r) {
        // moments: 0:M0 1:M1 2:M00 3:M01 4:M11 5:M000 6:M001 7:M011 8:M111
        float M[9];
#pragma unroll
        for (int i2 = 0; i2 < 9; ++i2) M[i2] = 0.f;
#pragma unroll
        for (int e = 0; e < 16; ++e) {
            float tv = ta[r][e], p = kp0[e], q2 = kp1[e];
            float u0 = tv * p, u1 = tv * q2;
            M[0] += u0; M[1] += u1;
            float u00 = u0 * p, u01 = u0 * q2, u11 = u1 * q2;
            M[2] += u00; M[3] += u01; M[4] += u11;
            M[5] += u00 * p; M[6] += u00 * q2; M[7] += u01 * q2; M[8] += u11 * q2;
        }
        // DPP reduce (no DS ops), result uniform via readlane
#pragma unroll
        for (int i2 = 0; i2 < 9; ++i2) M[i2] = wave_sum_bcast(M[i2]);

        float bf0 = 0.f, bf1 = 0.f;
#pragma unroll
        for (int it = 0; it < 8; ++it) {
            float q00 = bf0 * bf0, q01 = bf0 * bf1, q11 = bf1 * bf1;
            float s0 = M[0] - (bf0 * M[2] + bf1 * M[3]) + (q00 * M[5] + 2.f * q01 * M[6] + q11 * M[7]);
            float s1 = M[1] - (bf0 * M[3] + bf1 * M[4]) + (q00 * M[6] + 2.f * q01 * M[7] + q11 * M[8]);
            bf0 = bt0 * fastrcp(1.f + s0);
            bf1 = bt1 * fastrcp(1.f + s1);
        }
        const int R = R0 + r;
        if (lane == 0) { bff[(size_t)R * 2] = bf0; bff[(size_t)R * 2 + 1] = bf1; }

        // af -> bf16 (cvt_pk, RTNE) -> swizzled global image (validated)
        unsigned short* base = afb + (size_t)(R >> 5) * 32768 + (size_t)(R & 31) * 1024;
        const int s7 = R & 7;
#pragma unroll
        for (int c = 0; c < 4; ++c) {
            float v[4];
#pragma unroll
            for (int e = 0; e < 4; ++e) {
                int idx = c * 4 + e;
                v[e] = ta[r][idx] * fastrcp(1.f + bf0 * kp0[idx] + bf1 * kp1[idx]);
            }
            uint2 pk;
            pk.x = cvt_pk_bf16(v[0], v[1]);
            pk.y = cvt_pk_bf16(v[2], v[3]);
            int cg = c * 4 + (lane >> 4);
            int cl = (lane >> 1) & 7;
            int off = (cg * 8 + (cl ^ s7)) * 8 + (lane & 1) * 4;
            *(uint2*)(base + off) = pk;
        }
    }
}

// =====================================================================
// Kernel 2: GEMM + combine, BM=64 (unchanged — validated round 8).
// 256 blocks (1/CU), 512 threads. Stages TWO consecutive 64KB af images
// (contiguous 128 KB, linear copy) into a 128 KB LDS tile, split into
// two K-halves so half the stage latency hides under half-0 MFMA.
// Wave (h,q) = (w>>2, w&3): h picks image/row-half, q picks n-tiles
// {q,q+4,q+8,q+12}. B L2 traffic = 128 MB distinct + L1-shared dups.
// =====================================================================
__global__ __launch_bounds__(512, 2) void gemm_kernel(
    const unsigned short* __restrict__ afb,  // [512 images][32768] bf16
    const unsigned short* __restrict__ Vtf,  // fragment-major bf16
    const float* __restrict__ bff,           // [16384][2] f32
    const float* __restrict__ bias,          // [128] f32
    float* __restrict__ out)                 // [16384][128] f32
{
    __shared__ __align__(16) unsigned short lA[64 * 1024];   // 128 KB

    const int t    = threadIdx.x;
    const int lane = t & 63;
    const int w    = t >> 6;        // wave id 0..7
    const int mtile = blockIdx.x;   // 0..255

    const unsigned short* img = afb + (size_t)mtile * 65536;  // 2 images, contiguous

    // stage K-half hh: per row (64 rows), 512 elems (1 KB) at row*1024 + hh*512.
    auto stage = [&](int hh) {
#pragma unroll
        for (int i = 0; i < 8; ++i) {
            int s = i * 512 + t;                       // 0..4095
            int off = (s >> 6) * 1024 + hh * 512 + (s & 63) * 8;
            __builtin_amdgcn_global_load_lds(GLB_PTR(img + off), LDS_PTR(&lA[off]), 16, 0, 0);
        }
    };

    const int rr = lane & 15;      // row/col within 16-tile
    const int hb = lane >> 4;      // quarter-wave
    const int rx = rr & 7;         // A-swizzle key
    const int q  = w & 3;          // n-quad: tiles {q, q+4, q+8, q+12}
    const int h  = w >> 2;         // row-half: rows h*32 .. h*32+31 (image h)

    const unsigned short* pB = Vtf + (size_t)q * 16384 + hb * 128 + rr * 8;

    stage(0);

    f32x4_t acc[2][4];
#pragma unroll
    for (int i = 0; i < 2; ++i)
#pragma unroll
        for (int j = 0; j < 4; ++j) acc[i][j] = (f32x4_t){0.f, 0.f, 0.f, 0.f};

    bf16x8_t fbA[4], fbB[4];

    auto loadB = [&](bf16x8_t* fb, int k0, int kk) {
        int ke = k0 * 16 + kk * 512;              // uniform elem offset
        fb[0] = *(const bf16x8_t*)(pB + ke);            // tile q
        fb[1] = *(const bf16x8_t*)(pB + ke + 65536);    // tile q+4
        fb[2] = *(const bf16x8_t*)(pB + ke + 131072);   // tile q+8
        fb[3] = *(const bf16x8_t*)(pB + ke + 196608);   // tile q+12
    };
    auto compute = [&](const bf16x8_t* fb, int k0, int kk) {
        const int cq = kk * 4 + hb;
        bf16x8_t fa[2];
#pragma unroll
        for (int i = 0; i < 2; ++i) {
            int r = h * 32 + i * 16 + rr;
            fa[i] = *(const bf16x8_t*)(&lA[((r * 128) + (k0 >> 6) * 8 + (cq ^ rx)) * 8]);
        }
#pragma unroll
        for (int i = 0; i < 2; ++i)
#pragma unroll
            for (int j = 0; j < 4; ++j)
                acc[i][j] = __builtin_amdgcn_mfma_f32_16x16x32_bf16(fa[i], fb[j], acc[i][j], 0, 0, 0);
    };

    loadB(fbA, 0, 0);
    loadB(fbB, 0, 1);
    __syncthreads();   // drains vmcnt(0): half 0 of lA ready
    stage(1);          // issue half-1 stage; drains at next barrier

#pragma unroll 1
    for (int k0 = 0; k0 < 512; k0 += 64) {
        __builtin_amdgcn_s_setprio(1);
        compute(fbA, k0, 0);
        __builtin_amdgcn_s_setprio(0);
        loadB(fbA, k0 + 64, 0);
        __builtin_amdgcn_s_setprio(1);
        compute(fbB, k0, 1);
        __builtin_amdgcn_s_setprio(0);
        loadB(fbB, k0 + 64, 1);
    }
    __syncthreads();   // drains vmcnt(0): half 1 of lA ready
#pragma unroll 1
    for (int k0 = 512; k0 < AD; k0 += 64) {
        __builtin_amdgcn_s_setprio(1);
        compute(fbA, k0, 0);
        __builtin_amdgcn_s_setprio(0);
        if (k0 + 64 < AD) loadB(fbA, k0 + 64, 0);
        __builtin_amdgcn_s_setprio(1);
        compute(fbB, k0, 1);
        __builtin_amdgcn_s_setprio(0);
        if (k0 + 64 < AD) loadB(fbB, k0 + 64, 1);
    }

    // epilogue: C/D layout col = lane&15 (n), row = (lane>>4)*4 + reg (m).
    // (acc[i][jj], acc[i][jj+2]) pair at y = q*16 + jj*64 + rr and y+128.
#pragma unroll
    for (int i = 0; i < 2; ++i) {
        int mbase = mtile * 64 + h * 32 + i * 16 + hb * 4;
        float2 bfv[4];
#pragma unroll
        for (int r = 0; r < 4; ++r)
            bfv[r] = *(const float2*)(bff + (size_t)(mbase + r) * 2);
#pragma unroll
        for (int jj = 0; jj < 2; ++jj) {
            int y = q * 16 + jj * 64 + rr;          // jj=0: tile q; jj=1: tile q+4
            float bv = bias[y];
#pragma unroll
            for (int r = 0; r < 4; ++r) {
                float val = bfv[r].x * acc[i][jj][r] + bfv[r].y * acc[i][jj + 2][r] + bv;
                out[(size_t)(mbase + r) * YD + y] = val;
            }
        }
    }
}

// =====================================================================
extern "C" void kernel_launch(void* const* d_in, const int* in_sizes, int n_in,
                              void* d_out, int out_size, void* d_ws, size_t ws_size,
                              hipStream_t stream) {
    const float* AT  = (const float*)d_in[0];  // [16384][1024] f32
    const float* Kq  = (const float*)d_in[1];  // [1024][2] f32
    const float* BTv = (const float*)d_in[2];  // [2] f32
    const float* U   = (const float*)d_in[3];  // [2048][128] f32
    const float* bia = (const float*)d_in[4];  // [128] f32
    float* out = (float*)d_out;

    char* ws = (char*)d_ws;
    unsigned short* Vtf = (unsigned short*)ws;                    // 512 KB
    unsigned short* afb = (unsigned short*)(ws + 524288);         // 32 MB
    float*          bff = (float*)(ws + 524288 + 33554432);       // 128 KB

    prep_kernel<<<dim3(NB / 16), dim3(512), 0, stream>>>(AT, Kq, BTv, U, Vtf, afb, bff);
    gemm_kernel<<<dim3(NB / 64), dim3(512), 0, stream>>>(afb, Vtf, bff, bia, out);
}

// Round 10
// 119.938 us; speedup vs baseline: 1.0592x; 1.0328x over previous
//
#include <hip/hip_runtime.h>

// ---------- helpers ----------
__device__ __forceinline__ unsigned short f2b(float f) {
    unsigned int u = __builtin_bit_cast(unsigned int, f);
    u += 0x7fffu + ((u >> 16) & 1u);   // round-to-nearest-even
    return (unsigned short)(u >> 16);
}
__device__ __forceinline__ float fastrcp(float x) {
    return __builtin_amdgcn_rcpf(x);   // ~1e-7 rel err, invisible under bf16
}
// packed f32x2 -> bf16x2 (RTNE, same rounding as f2b), 1 instruction
__device__ __forceinline__ unsigned int cvt_pk_bf16(float lo, float hi) {
    unsigned int r;
    asm("v_cvt_pk_bf16_f32 %0, %1, %2" : "=v"(r) : "v"(lo), "v"(hi));
    return r;
}
// DPP wave64 sum: after chain, lane 63 holds the full sum; broadcast via readlane.
template<int CTRL>
__device__ __forceinline__ float dpp_add(float x) {
    int s = __builtin_amdgcn_update_dpp(0, __builtin_bit_cast(int, x), CTRL, 0xf, 0xf, true);
    return x + __builtin_bit_cast(float, s);
}
__device__ __forceinline__ float wave_sum_bcast(float x) {
    x = dpp_add<0x111>(x);   // row_shr:1
    x = dpp_add<0x112>(x);   // row_shr:2
    x = dpp_add<0x114>(x);   // row_shr:4
    x = dpp_add<0x118>(x);   // row_shr:8  -> lane 15/31/47/63 = row sums
    x = dpp_add<0x142>(x);   // row_bcast:15
    x = dpp_add<0x143>(x);   // row_bcast:31 -> lane 63 = total
    return __builtin_bit_cast(float,
        __builtin_amdgcn_readlane(__builtin_bit_cast(int, x), 63));
}

typedef short bf16x8_t __attribute__((ext_vector_type(8)));
typedef float f32x4_t  __attribute__((ext_vector_type(4)));

// Problem dims
#define NB   16384   // batch
#define AD   1024    // A dim
#define YD   128     // output dim

// =====================================================================
// Kernel 1: Vt in FRAGMENT-MAJOR layout (unchanged — validated).
//   Logical B row n (0..255), col a (0..1023):  val = Kp[a][n>>7]*U[2a+(n>>7)][n&127]
//   Physical: T=n>>4, rr=n&15, CQ=a>>3, e=a&7
//             Vtf[T*16384 + CQ*128 + rr*8 + e]
// =====================================================================
__global__ __launch_bounds__(256) void vt_kernel(
    const float* __restrict__ Kq,   // [1024][2] f32
    const float* __restrict__ U,    // [2048][128] f32
    unsigned short* __restrict__ Vtf) // [16][128][16][8] bf16
{
    int o  = blockIdx.x * 256 + threadIdx.x;
    int T  = o >> 14;
    int CQ = (o >> 7) & 127;
    int rr = (o >> 3) & 15;
    int e  = o & 7;
    int n  = T * 16 + rr;
    int a  = CQ * 8 + e;
    int j  = n >> 7;
    int y  = n & 127;
    float k  = Kq[2 * a + j];
    float uv = U[(size_t)(2 * a + j) * YD + y];
    Vtf[o] = f2b(k * k * uv);
}

// =====================================================================
// Kernel 2: FUSED row-solve + GEMM + combine.  (R4 — empirical best)
// 512 threads (8 waves), BM=32 rows/block, 512 blocks.
// LDS = 64KB A-tile + 256B bf -> 2 blocks/CU.
// Phase 1: wave w owns rows w*4..w*4+3 (2-row reg dbuf). Moments ->
//          DPP wave-sum (no DS ops) -> 8-iter closed-form solve ->
//          af bf16 via v_cvt_pk_bf16_f32 into swizzled LDS A-tile.
// Phase 2: barrier-free k-loop; wave w: h=w>>2 owns m-rows h*16..+15,
//          q=w&3 owns n-tiles {2q,2q+1,2q+8,2q+9}. A frags from LDS
//          (1 ds_read/kk), B frags reg-dbuf straight from L2.
// Epilogue: wave writes 32 CONTIGUOUS cols (full 128B lines).
// =====================================================================
__global__ __launch_bounds__(512, 4) void fused_kernel(
    const float* __restrict__ AT,            // [16384][1024] f32
    const float* __restrict__ Kq,            // [1024][2] f32
    const float* __restrict__ BTv,           // [2] f32
    const unsigned short* __restrict__ Vtf,  // fragment-major bf16
    const float* __restrict__ bias,          // [128] f32
    float* __restrict__ out)                 // [16384][128] f32
{
    __shared__ __align__(16) unsigned short lA[32 * 1024];    // 64 KB
    __shared__ float lbf[32][2];

    const int t    = threadIdx.x;
    const int lane = t & 63;
    const int w    = t >> 6;          // wave id 0..7
    const int mtile = blockIdx.x;     // 0..511

    // =================== Phase 1: row solve (4 rows/wave) ===================
    // lane owns columns a = c*256 + lane*4 + e, c=0..3, e=0..3
    float kp0[16], kp1[16];
#pragma unroll
    for (int c = 0; c < 4; ++c) {
        int base = c * 256 + lane * 4;
        float4 k0v = *(const float4*)(Kq + 2 * base);
        float4 k1v = *(const float4*)(Kq + 2 * base + 4);
        kp0[c * 4 + 0] = k0v.x * k0v.x; kp1[c * 4 + 0] = k0v.y * k0v.y;
        kp0[c * 4 + 1] = k0v.z * k0v.z; kp1[c * 4 + 1] = k0v.w * k0v.w;
        kp0[c * 4 + 2] = k1v.x * k1v.x; kp1[c * 4 + 2] = k1v.y * k1v.y;
        kp0[c * 4 + 3] = k1v.z * k1v.z; kp1[c * 4 + 3] = k1v.w * k1v.w;
    }
    const float bt0 = BTv[0], bt1 = BTv[1];

    const float* atb = AT + (size_t)(mtile * 32 + w * 4) * AD;

    float ta[2][16];   // 2-row double buffer, statically indexed (full unroll)
#pragma unroll
    for (int c = 0; c < 4; ++c) {
        float4 av = *(const float4*)(atb + c * 256 + lane * 4);
        ta[0][c * 4 + 0] = av.x; ta[0][c * 4 + 1] = av.y;
        ta[0][c * 4 + 2] = av.z; ta[0][c * 4 + 3] = av.w;
    }

#pragma unroll
    for (int r = 0; r < 4; ++r) {
        const int cur = r & 1, nxt = cur ^ 1;
        if (r < 3) {
#pragma unroll
            for (int c = 0; c < 4; ++c) {
                float4 av = *(const float4*)(atb + (size_t)(r + 1) * AD + c * 256 + lane * 4);
                ta[nxt][c * 4 + 0] = av.x; ta[nxt][c * 4 + 1] = av.y;
                ta[nxt][c * 4 + 2] = av.z; ta[nxt][c * 4 + 3] = av.w;
            }
        }

        // moments: 0:M0 1:M1 2:M00 3:M01 4:M11 5:M000 6:M001 7:M011 8:M111
        float M[9];
#pragma unroll
        for (int i2 = 0; i2 < 9; ++i2) M[i2] = 0.f;
#pragma unroll
        for (int e = 0; e < 16; ++e) {
            float tv = ta[cur][e], p = kp0[e], q2 = kp1[e];
            float u0 = tv * p, u1 = tv * q2;
            M[0] += u0; M[1] += u1;
            float u00 = u0 * p, u01 = u0 * q2, u11 = u1 * q2;
            M[2] += u00; M[3] += u01; M[4] += u11;
            M[5] += u00 * p; M[6] += u00 * q2; M[7] += u01 * q2; M[8] += u11 * q2;
        }
        // DPP reduce (no LDS/DS ops), result uniform via readlane
#pragma unroll
        for (int i2 = 0; i2 < 9; ++i2) M[i2] = wave_sum_bcast(M[i2]);

        float bf0 = 0.f, bf1 = 0.f;
#pragma unroll
        for (int it = 0; it < 8; ++it) {
            float q00 = bf0 * bf0, q01 = bf0 * bf1, q11 = bf1 * bf1;
            float s0 = M[0] - (bf0 * M[2] + bf1 * M[3]) + (q00 * M[5] + 2.f * q01 * M[6] + q11 * M[7]);
            float s1 = M[1] - (bf0 * M[3] + bf1 * M[4]) + (q00 * M[6] + 2.f * q01 * M[7] + q11 * M[8]);
            bf0 = bt0 * fastrcp(1.f + s0);
            bf1 = bt1 * fastrcp(1.f + s1);
        }
        const int m = w * 4 + r;
        if (lane == 0) { lbf[m][0] = bf0; lbf[m][1] = bf1; }

        // af -> bf16 (cvt_pk, RTNE) -> swizzled LDS A-tile (layout unchanged)
#pragma unroll
        for (int c = 0; c < 4; ++c) {
            float v[4];
#pragma unroll
            for (int e = 0; e < 4; ++e) {
                int idx = c * 4 + e;
                v[e] = ta[cur][idx] * fastrcp(1.f + bf0 * kp0[idx] + bf1 * kp1[idx]);
            }
            uint2 pk;
            pk.x = cvt_pk_bf16(v[0], v[1]);
            pk.y = cvt_pk_bf16(v[2], v[3]);
            int cg = c * 4 + (lane >> 4);
            int cl = (lane >> 1) & 7;
            int off = (m * 128 + cg * 8 + (cl ^ (m & 7))) * 8 + (lane & 1) * 4;
            *(uint2*)(&lA[off]) = pk;
        }
    }

    __syncthreads();   // the ONLY barrier: lA/lbf now visible to all waves

    // =================== Phase 2: barrier-free GEMM ===================
    const int rr = lane & 15;      // row/col within 16-tile
    const int hb = lane >> 4;      // quarter-wave
    const int q  = w & 3;          // n-quad: tiles {2q, 2q+1, 2q+8, 2q+9}
    const int h  = w >> 2;         // m-half: rows h*16 .. h*16+15
    const int rx = rr & 7;         // A-swizzle key ((h*16+rr)&7 == rr&7)

    const int lanePart = hb * 128 + rr * 8;                  // lane-varying part
    const unsigned short* bq = Vtf + (size_t)(2 * q) * 16384 + lanePart;

    f32x4_t acc[4];
#pragma unroll
    for (int j = 0; j < 4; ++j) acc[j] = (f32x4_t){0.f, 0.f, 0.f, 0.f};

    bf16x8_t fbA[4], fbB[4];

    auto loadB = [&](bf16x8_t* fb, int k0, int kk) {
        int ke = k0 * 16 + kk * 512;              // uniform elem offset
        fb[0] = *(const bf16x8_t*)(bq + ke);            // tile 2q
        fb[1] = *(const bf16x8_t*)(bq + ke + 16384);    // tile 2q+1
        fb[2] = *(const bf16x8_t*)(bq + ke + 131072);   // tile 2q+8
        fb[3] = *(const bf16x8_t*)(bq + ke + 147456);   // tile 2q+9
    };
    auto compute = [&](const bf16x8_t* fb, int k0, int kk) {
        const int cq = kk * 4 + hb;
        bf16x8_t fa = *(const bf16x8_t*)(
            &lA[(((h * 16 + rr) * 128) + (k0 >> 6) * 8 + (cq ^ rx)) * 8]);
#pragma unroll
        for (int j = 0; j < 4; ++j)
            acc[j] = __builtin_amdgcn_mfma_f32_16x16x32_bf16(fa, fb[j], acc[j], 0, 0, 0);
    };

    loadB(fbA, 0, 0);
    loadB(fbB, 0, 1);
#pragma unroll 1
    for (int k0 = 0; k0 < AD; k0 += 64) {
        __builtin_amdgcn_s_setprio(1);
        compute(fbA, k0, 0);
        __builtin_amdgcn_s_setprio(0);
        if (k0 + 64 < AD) loadB(fbA, k0 + 64, 0);
        __builtin_amdgcn_s_setprio(1);
        compute(fbB, k0, 1);
        __builtin_amdgcn_s_setprio(0);
        if (k0 + 64 < AD) loadB(fbB, k0 + 64, 1);
    }

    // =================== Epilogue ===================
    // C/D layout: col = lane&15 (n within tile), row = (lane>>4)*4 + reg.
    // acc[jj] (tile 2q+jj, y-cols) pairs with acc[jj+2] (tile 2q+8+jj, y+128).
    // Wave writes cols q*32 .. q*32+31: full 128B lines.
    const int mloc  = h * 16 + hb * 4;
    const int mbase = mtile * 32 + mloc;
    float2 bfv[4];
#pragma unroll
    for (int r = 0; r < 4; ++r)
        bfv[r] = *(const float2*)(&lbf[mloc + r][0]);
#pragma unroll
    for (int jj = 0; jj < 2; ++jj) {
        int y = q * 32 + jj * 16 + rr;
        float bv = bias[y];
#pragma unroll
        for (int r = 0; r < 4; ++r) {
            float val = bfv[r].x * acc[jj][r] + bfv[r].y * acc[jj + 2][r] + bv;
            out[(size_t)(mbase + r) * YD + y] = val;
        }
    }
}

// =====================================================================
extern "C" void kernel_launch(void* const* d_in, const int* in_sizes, int n_in,
                              void* d_out, int out_size, void* d_ws, size_t ws_size,
                              hipStream_t stream) {
    const float* AT  = (const float*)d_in[0];  // [16384][1024] f32
    const float* Kq  = (const float*)d_in[1];  // [1024][2] f32
    const float* BTv = (const float*)d_in[2];  // [2] f32
    const float* U   = (const float*)d_in[3];  // [2048][128] f32
    const float* bia = (const float*)d_in[4];  // [128] f32
    float* out = (float*)d_out;

    unsigned short* Vtf = (unsigned short*)d_ws;  // 512 KB bf16 fragment-major

    vt_kernel<<<dim3(1024), dim3(256), 0, stream>>>(Kq, U, Vtf);
    fused_kernel<<<dim3(NB / 32), dim3(512), 0, stream>>>(AT, Kq, BTv, Vtf, bia, out);
}

// Round 11
// 118.219 us; speedup vs baseline: 1.0746x; 1.0145x over previous
//
#include <hip/hip_runtime.h>

// ---------- helpers ----------
__device__ __forceinline__ unsigned short f2b(float f) {
    unsigned int u = __builtin_bit_cast(unsigned int, f);
    u += 0x7fffu + ((u >> 16) & 1u);   // round-to-nearest-even
    return (unsigned short)(u >> 16);
}
__device__ __forceinline__ float fastrcp(float x) {
    return __builtin_amdgcn_rcpf(x);   // ~1e-7 rel err, invisible under bf16
}
// packed f32x2 -> bf16x2 (RTNE, same rounding as f2b), 1 instruction
__device__ __forceinline__ unsigned int cvt_pk_bf16(float lo, float hi) {
    unsigned int r;
    asm("v_cvt_pk_bf16_f32 %0, %1, %2" : "=v"(r) : "v"(lo), "v"(hi));
    return r;
}
// DPP wave64 sum: after chain, lane 63 holds the full sum; broadcast via readlane.
template<int CTRL>
__device__ __forceinline__ float dpp_add(float x) {
    int s = __builtin_amdgcn_update_dpp(0, __builtin_bit_cast(int, x), CTRL, 0xf, 0xf, true);
    return x + __builtin_bit_cast(float, s);
}
__device__ __forceinline__ float wave_sum_bcast(float x) {
    x = dpp_add<0x111>(x);   // row_shr:1
    x = dpp_add<0x112>(x);   // row_shr:2
    x = dpp_add<0x114>(x);   // row_shr:4
    x = dpp_add<0x118>(x);   // row_shr:8  -> lane 15/31/47/63 = row sums
    x = dpp_add<0x142>(x);   // row_bcast:15
    x = dpp_add<0x143>(x);   // row_bcast:31 -> lane 63 = total
    return __builtin_bit_cast(float,
        __builtin_amdgcn_readlane(__builtin_bit_cast(int, x), 63));
}

typedef short bf16x8_t __attribute__((ext_vector_type(8)));
typedef float f32x4_t  __attribute__((ext_vector_type(4)));
typedef float f32x2_t  __attribute__((ext_vector_type(2)));

// Problem dims
#define NB   16384   // batch
#define AD   1024    // A dim
#define YD   128     // output dim

// =====================================================================
// Kernel 1: Vt in FRAGMENT-MAJOR layout (unchanged — validated).
//   Logical B row n (0..255), col a (0..1023):  val = Kp[a][n>>7]*U[2a+(n>>7)][n&127]
//   Physical: T=n>>4, rr=n&15, CQ=a>>3, e=a&7
//             Vtf[T*16384 + CQ*128 + rr*8 + e]
// =====================================================================
__global__ __launch_bounds__(256) void vt_kernel(
    const float* __restrict__ Kq,   // [1024][2] f32
    const float* __restrict__ U,    // [2048][128] f32
    unsigned short* __restrict__ Vtf) // [16][128][16][8] bf16
{
    int o  = blockIdx.x * 256 + threadIdx.x;
    int T  = o >> 14;
    int CQ = (o >> 7) & 127;
    int rr = (o >> 3) & 15;
    int e  = o & 7;
    int n  = T * 16 + rr;
    int a  = CQ * 8 + e;
    int j  = n >> 7;
    int y  = n & 127;
    float k  = Kq[2 * a + j];
    float uv = U[(size_t)(2 * a + j) * YD + y];
    Vtf[o] = f2b(k * k * uv);
}

// =====================================================================
// Kernel 2: FUSED row-solve + GEMM + combine.  (R4 structure — empirical
// best, reproduced 118.8/119.9.)  Phase-1 math rewritten on f32x2 vector
// pairs so the backend emits packed v_pk_fma_f32/v_pk_mul_f32 (gfx90a+):
// halves the moments/af VALU instruction count. Per-element arithmetic,
// rounding (RTNE via cvt_pk), swizzle, phase 2 and epilogue are
// unchanged from the validated kernel.
// 512 threads (8 waves), BM=32 rows/block, 512 blocks.
// LDS = 64KB A-tile + 256B bf -> 2 blocks/CU.
// =====================================================================
__global__ __launch_bounds__(512, 4) void fused_kernel(
    const float* __restrict__ AT,            // [16384][1024] f32
    const float* __restrict__ Kq,            // [1024][2] f32
    const float* __restrict__ BTv,           // [2] f32
    const unsigned short* __restrict__ Vtf,  // fragment-major bf16
    const float* __restrict__ bias,          // [128] f32
    float* __restrict__ out)                 // [16384][128] f32
{
    __shared__ __align__(16) unsigned short lA[32 * 1024];    // 64 KB
    __shared__ float lbf[32][2];

    const int t    = threadIdx.x;
    const int lane = t & 63;
    const int w    = t >> 6;          // wave id 0..7
    const int mtile = blockIdx.x;     // 0..511

    // =================== Phase 1: row solve (4 rows/wave) ===================
    // lane owns columns a = c*256 + lane*4 + e, e=0..3; pairs (e0,e1),(e2,e3)
    // pair index p2 = c*2 + h, h=0,1.
    f32x2_t kp0[8], kp1[8];
#pragma unroll
    for (int c = 0; c < 4; ++c) {
        int base = c * 256 + lane * 4;
        float4 k0v = *(const float4*)(Kq + 2 * base);      // K[a0][0..1], K[a1][0..1]
        float4 k1v = *(const float4*)(Kq + 2 * base + 4);  // K[a2][0..1], K[a3][0..1]
        kp0[c * 2 + 0] = (f32x2_t){k0v.x * k0v.x, k0v.z * k0v.z};
        kp1[c * 2 + 0] = (f32x2_t){k0v.y * k0v.y, k0v.w * k0v.w};
        kp0[c * 2 + 1] = (f32x2_t){k1v.x * k1v.x, k1v.z * k1v.z};
        kp1[c * 2 + 1] = (f32x2_t){k1v.y * k1v.y, k1v.w * k1v.w};
    }
    const float bt0 = BTv[0], bt1 = BTv[1];

    const float* atb = AT + (size_t)(mtile * 32 + w * 4) * AD;

    f32x2_t ta[2][8];   // 2-row double buffer of element pairs
#pragma unroll
    for (int c = 0; c < 4; ++c) {
        float4 av = *(const float4*)(atb + c * 256 + lane * 4);
        ta[0][c * 2 + 0] = (f32x2_t){av.x, av.y};
        ta[0][c * 2 + 1] = (f32x2_t){av.z, av.w};
    }

#pragma unroll
    for (int r = 0; r < 4; ++r) {
        const int cur = r & 1, nxt = cur ^ 1;
        if (r < 3) {
#pragma unroll
            for (int c = 0; c < 4; ++c) {
                float4 av = *(const float4*)(atb + (size_t)(r + 1) * AD + c * 256 + lane * 4);
                ta[nxt][c * 2 + 0] = (f32x2_t){av.x, av.y};
                ta[nxt][c * 2 + 1] = (f32x2_t){av.z, av.w};
            }
        }

        // moments (packed pairs): 0:M0 1:M1 2:M00 3:M01 4:M11 5:M000 6:M001 7:M011 8:M111
        f32x2_t Mv[9];
#pragma unroll
        for (int i2 = 0; i2 < 9; ++i2) Mv[i2] = (f32x2_t){0.f, 0.f};
#pragma unroll
        for (int e = 0; e < 8; ++e) {
            f32x2_t tv = ta[cur][e], p = kp0[e], q2 = kp1[e];
            f32x2_t u0 = tv * p, u1 = tv * q2;
            Mv[0] += u0; Mv[1] += u1;
            f32x2_t u00 = u0 * p, u01 = u0 * q2, u11 = u1 * q2;
            Mv[2] += u00; Mv[3] += u01; Mv[4] += u11;
            Mv[5] += u00 * p; Mv[6] += u00 * q2; Mv[7] += u01 * q2; Mv[8] += u11 * q2;
        }
        float M[9];
#pragma unroll
        for (int i2 = 0; i2 < 9; ++i2) M[i2] = Mv[i2].x + Mv[i2].y;
        // DPP reduce (no LDS/DS ops), result uniform via readlane
#pragma unroll
        for (int i2 = 0; i2 < 9; ++i2) M[i2] = wave_sum_bcast(M[i2]);

        float bf0 = 0.f, bf1 = 0.f;
#pragma unroll
        for (int it = 0; it < 8; ++it) {
            float q00 = bf0 * bf0, q01 = bf0 * bf1, q11 = bf1 * bf1;
            float s0 = M[0] - (bf0 * M[2] + bf1 * M[3]) + (q00 * M[5] + 2.f * q01 * M[6] + q11 * M[7]);
            float s1 = M[1] - (bf0 * M[3] + bf1 * M[4]) + (q00 * M[6] + 2.f * q01 * M[7] + q11 * M[8]);
            bf0 = bt0 * fastrcp(1.f + s0);
            bf1 = bt1 * fastrcp(1.f + s1);
        }
        const int m = w * 4 + r;
        if (lane == 0) { lbf[m][0] = bf0; lbf[m][1] = bf1; }

        // af -> bf16 (cvt_pk, RTNE) -> swizzled LDS A-tile (layout unchanged)
        const f32x2_t bf0v = (f32x2_t){bf0, bf0};
        const f32x2_t bf1v = (f32x2_t){bf1, bf1};
        const f32x2_t onev = (f32x2_t){1.f, 1.f};
#pragma unroll
        for (int c = 0; c < 4; ++c) {
            f32x2_t t0 = ta[cur][c * 2 + 0], t1 = ta[cur][c * 2 + 1];
            f32x2_t d0 = onev + bf0v * kp0[c * 2 + 0] + bf1v * kp1[c * 2 + 0];
            f32x2_t d1 = onev + bf0v * kp0[c * 2 + 1] + bf1v * kp1[c * 2 + 1];
            float v0 = t0.x * fastrcp(d0.x);
            float v1 = t0.y * fastrcp(d0.y);
            float v2 = t1.x * fastrcp(d1.x);
            float v3 = t1.y * fastrcp(d1.y);
            uint2 pk;
            pk.x = cvt_pk_bf16(v0, v1);
            pk.y = cvt_pk_bf16(v2, v3);
            int cg = c * 4 + (lane >> 4);
            int cl = (lane >> 1) & 7;
            int off = (m * 128 + cg * 8 + (cl ^ (m & 7))) * 8 + (lane & 1) * 4;
            *(uint2*)(&lA[off]) = pk;
        }
    }

    __syncthreads();   // the ONLY barrier: lA/lbf now visible to all waves

    // =================== Phase 2: barrier-free GEMM ===================
    const int rr = lane & 15;      // row/col within 16-tile
    const int hb = lane >> 4;      // quarter-wave
    const int q  = w & 3;          // n-quad: tiles {2q, 2q+1, 2q+8, 2q+9}
    const int h  = w >> 2;         // m-half: rows h*16 .. h*16+15
    const int rx = rr & 7;         // A-swizzle key ((h*16+rr)&7 == rr&7)

    const int lanePart = hb * 128 + rr * 8;                  // lane-varying part
    const unsigned short* bq = Vtf + (size_t)(2 * q) * 16384 + lanePart;

    f32x4_t acc[4];
#pragma unroll
    for (int j = 0; j < 4; ++j) acc[j] = (f32x4_t){0.f, 0.f, 0.f, 0.f};

    bf16x8_t fbA[4], fbB[4];

    auto loadB = [&](bf16x8_t* fb, int k0, int kk) {
        int ke = k0 * 16 + kk * 512;              // uniform elem offset
        fb[0] = *(const bf16x8_t*)(bq + ke);            // tile 2q
        fb[1] = *(const bf16x8_t*)(bq + ke + 16384);    // tile 2q+1
        fb[2] = *(const bf16x8_t*)(bq + ke + 131072);   // tile 2q+8
        fb[3] = *(const bf16x8_t*)(bq + ke + 147456);   // tile 2q+9
    };
    auto compute = [&](const bf16x8_t* fb, int k0, int kk) {
        const int cq = kk * 4 + hb;
        bf16x8_t fa = *(const bf16x8_t*)(
            &lA[(((h * 16 + rr) * 128) + (k0 >> 6) * 8 + (cq ^ rx)) * 8]);
#pragma unroll
        for (int j = 0; j < 4; ++j)
            acc[j] = __builtin_amdgcn_mfma_f32_16x16x32_bf16(fa, fb[j], acc[j], 0, 0, 0);
    };

    loadB(fbA, 0, 0);
    loadB(fbB, 0, 1);
#pragma unroll 1
    for (int k0 = 0; k0 < AD; k0 += 64) {
        __builtin_amdgcn_s_setprio(1);
        compute(fbA, k0, 0);
        __builtin_amdgcn_s_setprio(0);
        if (k0 + 64 < AD) loadB(fbA, k0 + 64, 0);
        __builtin_amdgcn_s_setprio(1);
        compute(fbB, k0, 1);
        __builtin_amdgcn_s_setprio(0);
        if (k0 + 64 < AD) loadB(fbB, k0 + 64, 1);
    }

    // =================== Epilogue ===================
    // C/D layout: col = lane&15 (n within tile), row = (lane>>4)*4 + reg.
    // acc[jj] (tile 2q+jj, y-cols) pairs with acc[jj+2] (tile 2q+8+jj, y+128).
    // Wave writes cols q*32 .. q*32+31: full 128B lines.
    const int mloc  = h * 16 + hb * 4;
    const int mbase = mtile * 32 + mloc;
    float2 bfv[4];
#pragma unroll
    for (int r = 0; r < 4; ++r)
        bfv[r] = *(const float2*)(&lbf[mloc + r][0]);
#pragma unroll
    for (int jj = 0; jj < 2; ++jj) {
        int y = q * 32 + jj * 16 + rr;
        float bv = bias[y];
#pragma unroll
        for (int r = 0; r < 4; ++r) {
            float val = bfv[r].x * acc[jj][r] + bfv[r].y * acc[jj + 2][r] + bv;
            out[(size_t)(mbase + r) * YD + y] = val;
        }
    }
}

// =====================================================================
extern "C" void kernel_launch(void* const* d_in, const int* in_sizes, int n_in,
                              void* d_out, int out_size, void* d_ws, size_t ws_size,
                              hipStream_t stream) {
    const float* AT  = (const float*)d_in[0];  // [16384][1024] f32
    const float* Kq  = (const float*)d_in[1];  // [1024][2] f32
    const float* BTv = (const float*)d_in[2];  // [2] f32
    const float* U   = (const float*)d_in[3];  // [2048][128] f32
    const float* bia = (const float*)d_in[4];  // [128] f32
    float* out = (float*)d_out;

    unsigned short* Vtf = (unsigned short*)d_ws;  // 512 KB bf16 fragment-major

    vt_kernel<<<dim3(1024), dim3(256), 0, stream>>>(Kq, U, Vtf);
    fused_kernel<<<dim3(NB / 32), dim3(512), 0, stream>>>(AT, Kq, BTv, Vtf, bia, out);
}